// Round 5
// baseline (194.854 us; speedup 1.0000x reference)
//
#include <hip/hip_runtime.h>
#include <stdint.h>

typedef unsigned short u16;
typedef __attribute__((ext_vector_type(8))) short short8;
typedef __attribute__((ext_vector_type(4))) float f32x4;
typedef __attribute__((ext_vector_type(16))) float f32x16;

typedef __attribute__((address_space(1))) void as1_void;
typedef __attribute__((address_space(3))) void as3_void;

__device__ inline u16 f2bf(float x) {
  uint32_t u = __float_as_uint(x);
  return (u16)((u + 0x7fffu + ((u >> 16) & 1u)) >> 16);
}

__device__ inline void gload16(const void* g, void* l) {
  __builtin_amdgcn_global_load_lds((as1_void*)g, (as3_void*)l, 16, 0, 0);
}

__device__ inline uint32_t cvtpk(float lo, float hi) {
  uint32_t d;
  asm("v_cvt_pk_bf16_f32 %0, %1, %2" : "=v"(d) : "v"(lo), "v"(hi));
  return d;
}

__device__ inline void plswap(uint32_t& a, uint32_t& b) {
  asm("v_permlane32_swap_b32 %0, %1" : "+v"(a), "+v"(b));
}

__device__ inline float fexp2(float x) {
  float r;
  asm("v_exp_f32 %0, %1" : "=v"(r) : "v"(x));
  return r;
}

// ---------------- f32 -> bf16 conversion ----------------
__global__ __launch_bounds__(256) void cvt_bf16_kernel(const float* __restrict__ in,
                                                       u16* __restrict__ out, int n4) {
  int i = blockIdx.x * 256 + threadIdx.x;
  if (i >= n4) return;
  float4 v = ((const float4*)in)[i];
  ushort4 o;
  o.x = f2bf(v.x); o.y = f2bf(v.y); o.z = f2bf(v.z); o.w = f2bf(v.w);
  ((ushort4*)out)[i] = o;
}

// 4 weight matrices (512x512 each) in one launch
__global__ __launch_bounds__(256) void cvt4_kernel(const float* __restrict__ a,
                                                   const float* __restrict__ b,
                                                   const float* __restrict__ c,
                                                   const float* __restrict__ d,
                                                   u16* oa, u16* ob, u16* oc, u16* od) {
  const float* in = blockIdx.y == 0 ? a : blockIdx.y == 1 ? b : blockIdx.y == 2 ? c : d;
  u16* out = blockIdx.y == 0 ? oa : blockIdx.y == 1 ? ob : blockIdx.y == 2 ? oc : od;
  int i = blockIdx.x * 256 + threadIdx.x;
  float4 v = ((const float4*)in)[i];
  ushort4 o;
  o.x = f2bf(v.x); o.y = f2bf(v.y); o.z = f2bf(v.z); o.w = f2bf(v.w);
  ((ushort4*)out)[i] = o;
}

// ---------------- GEMM (R2-verified): C[m,n] = (A[m,:].W[n,:] + bias[n])*prescale
// M=8192, N=512, K=512. Tile 128x128, 4 waves (2x2), BK=32, single buffer,
// gload16 staging + two __syncthreads per K-step.
template <int MODE>
__global__ __launch_bounds__(256) void gemm_bt(const u16* __restrict__ A,
                                               const u16* __restrict__ W,
                                               const float* __restrict__ bias,
                                               void* __restrict__ Cout, float prescale) {
  __shared__ u16 Al[128 * 32];
  __shared__ u16 Wl[128 * 32];
  const int tid = threadIdx.x;
  const int lane = tid & 63;
  const int wv = tid >> 6;
  const int c = lane & 15;
  const int g = lane >> 4;
  const int wr = wv >> 1, wc = wv & 1;
  const int m0 = blockIdx.x * 128;
  const int n0 = blockIdx.y * 128;

  f32x4 acc[4][4];
#pragma unroll
  for (int i = 0; i < 4; i++)
#pragma unroll
    for (int j = 0; j < 4; j++) acc[i][j] = (f32x4){0.f, 0.f, 0.f, 0.f};

  for (int kk = 0; kk < 512; kk += 32) {
    __syncthreads();
    {
      int t0 = tid;
      int r0 = t0 >> 2, c0 = t0 & 3;
      gload16(A + (size_t)(m0 + r0) * 512 + kk + c0 * 8, (char*)Al + (size_t)(wv * 64) * 16);
      gload16(W + (size_t)(n0 + r0) * 512 + kk + c0 * 8, (char*)Wl + (size_t)(wv * 64) * 16);
      int t1 = 256 + tid;
      int r1 = t1 >> 2, c1 = t1 & 3;
      gload16(A + (size_t)(m0 + r1) * 512 + kk + c1 * 8, (char*)Al + (size_t)(256 + wv * 64) * 16);
      gload16(W + (size_t)(n0 + r1) * 512 + kk + c1 * 8, (char*)Wl + (size_t)(256 + wv * 64) * 16);
    }
    __syncthreads();

    short8 af[4], wf[4];
#pragma unroll
    for (int ai = 0; ai < 4; ai++)
      af[ai] = *(const short8*)&Al[(wr * 64 + ai * 16 + c) * 32 + g * 8];
#pragma unroll
    for (int bj = 0; bj < 4; bj++)
      wf[bj] = *(const short8*)&Wl[(wc * 64 + bj * 16 + c) * 32 + g * 8];
#pragma unroll
    for (int ai = 0; ai < 4; ai++)
#pragma unroll
      for (int bj = 0; bj < 4; bj++)
        acc[ai][bj] = __builtin_amdgcn_mfma_f32_16x16x32_bf16(af[ai], wf[bj], acc[ai][bj], 0, 0, 0);
  }

#pragma unroll
  for (int ai = 0; ai < 4; ai++)
#pragma unroll
    for (int bj = 0; bj < 4; bj++)
#pragma unroll
      for (int r = 0; r < 4; r++) {
        int m = m0 + wr * 64 + ai * 16 + g * 4 + r;
        int n = n0 + wc * 64 + bj * 16 + c;
        float v = (acc[ai][bj][r] + bias[n]) * prescale;
        if (MODE == 2) {
          ((float*)Cout)[(size_t)m * 512 + n] = v;
        } else {
          int b = m >> 12, s = m & 4095;
          int h = n >> 6, d = n & 63;
          size_t idx;
          if (MODE == 0)
            idx = ((size_t)(b * 8 + h) * 4096 + s) * 64 + d;
          else
            idx = ((size_t)(b * 8 + h) * 64 + d) * 4096 + s;
          ((u16*)Cout)[idx] = f2bf(v);
        }
      }
}

// ---------------- Flash attention, R2 core + within-block split-KV x2 ------
// Grid 512 = 16 bh x 32 qtiles. Block 512 thr = 8 waves: half = w>>2 covers
// KV [half*2048, +2048); wq = w&3 owns 32 q-rows. Per-half K/V LDS [32][128]
// (R2 layout: row kv&31, 16B-chunk ((kv>>5)*8 + d/8) ^ (kv&15)), ds_write
// staged with reg prefetch (R2-verified). Online-max softmax (R2-verified).
// Final (m,l)-aware combine via LDS.
__global__ __launch_bounds__(512, 4) void attn_kernel(const u16* __restrict__ Qh,
                                                      const u16* __restrict__ Kh,
                                                      const u16* __restrict__ Vt,
                                                      u16* __restrict__ Oa) {
  __shared__ __align__(16) char smem[34816];  // staging 32KB; combine 33.5KB
  const int tid = threadIdx.x;
  const int lane = tid & 63;
  const int w = tid >> 6;
  const int half = w >> 2;
  const int wq = w & 3;
  const int c5 = lane & 31;
  const int h = lane >> 5;
  const int bh = blockIdx.x >> 5;
  const int qt = blockIdx.x & 31;
  const int q0 = qt * 128 + wq * 32;
  const u16* Qb = Qh + (size_t)bh * 262144;
  const u16* Kb = Kh + (size_t)bh * 262144 + (size_t)half * 2048 * 64;
  const u16* Vb = Vt + (size_t)bh * 262144 + half * 2048;

  u16* Kl = (u16*)(smem + half * 16384);         // [32][128]
  u16* Vl = (u16*)(smem + half * 16384 + 8192);  // [32][128]

  // Q B-frag (pre-scaled by log2e/8 in projection)
  short8 qf[4];
#pragma unroll
  for (int kd = 0; kd < 4; kd++)
    qf[kd] = *(const short8*)(Qb + (size_t)(q0 + c5) * 64 + kd * 16 + h * 8);

  f32x16 accO[2];
#pragma unroll
  for (int i = 0; i < 16; i++) { accO[0][i] = 0.f; accO[1][i] = 0.f; }
  float m_r = -1e30f, l_r = 0.f;

  // staging (R2 pattern): 256 threads of each half, 2 K + 2 V chunks each
  const int st = tid & 255;
  const int rA = st >> 3, e8 = st & 7;
  const int dstK = rA * 128 + ((e8 ^ (rA & 15)) << 3);  // u16 idx; chunk2 = ^64
  const size_t srcK0 = (size_t)rA * 64 + e8 * 8, srcK1 = srcK0 + 32 * 64;
  const size_t srcV0 = (size_t)rA * 4096 + e8 * 8, srcV1 = srcV0 + (size_t)32 * 4096;

  int4 k0 = *(const int4*)(Kb + srcK0);
  int4 k1 = *(const int4*)(Kb + srcK1);
  int4 v0 = *(const int4*)(Vb + srcV0);
  int4 v1 = *(const int4*)(Vb + srcV1);

  const int swz = c5 & 15;
  const int rowb = c5 * 128;

  for (int kv0 = 0; kv0 < 2048; kv0 += 64) {
    __syncthreads();
    *(int4*)&Kl[dstK] = k0; *(int4*)&Kl[dstK ^ 64] = k1;
    *(int4*)&Vl[dstK] = v0; *(int4*)&Vl[dstK ^ 64] = v1;
    __syncthreads();
    if (kv0 + 64 < 2048) {  // prefetch next tile into regs
      const u16* Kn = Kb + (size_t)(kv0 + 64) * 64;
      const u16* Vn = Vb + (kv0 + 64);
      k0 = *(const int4*)(Kn + srcK0); k1 = *(const int4*)(Kn + srcK1);
      v0 = *(const int4*)(Vn + srcV0); v1 = *(const int4*)(Vn + srcV1);
    }

    // S^T = K * Q^T : lane(c5,h): q=c5, kv = 32*kb + 4h + (r&3) + 8*(r>>2)
    f32x16 s0, s1;
#pragma unroll
    for (int i = 0; i < 16; i++) { s0[i] = 0.f; s1[i] = 0.f; }
#pragma unroll
    for (int kd = 0; kd < 4; kd++) {
      short8 kf0 = *(const short8*)&Kl[rowb + ((((kd << 1) + h) ^ swz) << 3)];
      short8 kf1 = *(const short8*)&Kl[rowb + (((8 + (kd << 1) + h) ^ swz) << 3)];
      s0 = __builtin_amdgcn_mfma_f32_32x32x16_bf16(kf0, qf[kd], s0, 0, 0, 0);
      s1 = __builtin_amdgcn_mfma_f32_32x32x16_bf16(kf1, qf[kd], s1, 0, 0, 0);
    }

    // online softmax, in-register (scores in log2 domain)
    float t[16];
#pragma unroll
    for (int i = 0; i < 16; i++) t[i] = fmaxf(s0[i], s1[i]);
#pragma unroll
    for (int stp = 8; stp > 0; stp >>= 1)
#pragma unroll
      for (int i = 0; i < 8; i++) if (i < stp) t[i] = fmaxf(t[i], t[i + stp]);
    float tm = fmaxf(t[0], __shfl_xor(t[0], 32));
    float mn = fmaxf(m_r, tm);
    float corr = fexp2(m_r - mn);
#pragma unroll
    for (int i = 0; i < 16; i++) { s0[i] = fexp2(s0[i] - mn); s1[i] = fexp2(s1[i] - mn); }
#pragma unroll
    for (int i = 0; i < 16; i++) t[i] = s0[i] + s1[i];
#pragma unroll
    for (int stp = 8; stp > 0; stp >>= 1)
#pragma unroll
      for (int i = 0; i < 8; i++) if (i < stp) t[i] += t[i + stp];
    float rs = t[0] + __shfl_xor(t[0], 32);
    l_r = l_r * corr + rs;
    m_r = mn;
#pragma unroll
    for (int i = 0; i < 16; i++) { accO[0][i] *= corr; accO[1][i] *= corr; }

    // P -> bf16 B-frag in-register (R2-verified cvt_pk + permlane32_swap)
    uint32_t pk0[4][2], pk1[4][2];
#pragma unroll
    for (int u = 0; u < 4; u++) {
      pk0[u][0] = cvtpk(s0[4 * u], s0[4 * u + 1]);
      pk0[u][1] = cvtpk(s0[4 * u + 2], s0[4 * u + 3]);
      pk1[u][0] = cvtpk(s1[4 * u], s1[4 * u + 1]);
      pk1[u][1] = cvtpk(s1[4 * u + 2], s1[4 * u + 3]);
    }
    short8 pa[4];
#pragma unroll
    for (int km = 0; km < 2; km++) {
      const int uA = (km & 1) * 2, uB = uA + 1;
      uint32_t a0 = pk0[uA][0], b0 = pk0[uB][0]; plswap(a0, b0);
      uint32_t a1 = pk0[uA][1], b1 = pk0[uB][1]; plswap(a1, b1);
      union { uint32_t u[4]; short8 s; } uu;
      uu.u[0] = a0; uu.u[1] = a1; uu.u[2] = b0; uu.u[3] = b1;
      pa[km] = uu.s;
    }
#pragma unroll
    for (int km = 2; km < 4; km++) {
      const int uA = (km & 1) * 2, uB = uA + 1;
      uint32_t a0 = pk1[uA][0], b0 = pk1[uB][0]; plswap(a0, b0);
      uint32_t a1 = pk1[uA][1], b1 = pk1[uB][1]; plswap(a1, b1);
      union { uint32_t u[4]; short8 s; } uu;
      uu.u[0] = a0; uu.u[1] = a1; uu.u[2] = b0; uu.u[3] = b1;
      pa[km] = uu.s;
    }

    // O^T += V^T * P^T
#pragma unroll
    for (int km = 0; km < 4; km++) {
      short8 vf0 = *(const short8*)&Vl[rowb + ((((km << 1) + h) ^ swz) << 3)];
      short8 vf1 = *(const short8*)&Vl[rowb + (((8 + (km << 1) + h) ^ swz) << 3)];
      accO[0] = __builtin_amdgcn_mfma_f32_32x32x16_bf16(vf0, pa[km], accO[0], 0, 0, 0);
      accO[1] = __builtin_amdgcn_mfma_f32_32x32x16_bf16(vf1, pa[km], accO[1], 0, 0, 0);
    }
  }

  // ---- (m,l)-aware combine of the two halves via LDS ----
  __syncthreads();  // all compute done; smem reusable
  float* Of = (float*)smem;                    // 4 regions x 32 x 65 f32
  float* Ml = (float*)(smem + 33280);          // 4 x 32 x 2 f32
  if (half == 1) {
    float* dst = Of + wq * 2080;
#pragma unroll
    for (int db = 0; db < 2; db++)
#pragma unroll
      for (int r = 0; r < 16; r++) {
        int d = db * 32 + 4 * h + (r & 3) + 8 * (r >> 2);
        dst[c5 * 65 + d] = accO[db][r];
      }
    if (h == 0) { Ml[wq * 64 + c5 * 2] = m_r; Ml[wq * 64 + c5 * 2 + 1] = l_r; }
  }
  __syncthreads();
  if (half == 0) {
    const float* src = Of + wq * 2080;
    float m1 = Ml[wq * 64 + c5 * 2], l1 = Ml[wq * 64 + c5 * 2 + 1];
    float ms = fmaxf(m_r, m1);
    float a0 = fexp2(m_r - ms), a1 = fexp2(m1 - ms);
    float inv = 1.f / (l_r * a0 + l1 * a1);
    const int b = bh >> 3, hh = bh & 7;
    u16* Ob = Oa + (size_t)(b * 4096 + q0 + c5) * 512 + hh * 64;
#pragma unroll
    for (int db = 0; db < 2; db++)
#pragma unroll
      for (int r = 0; r < 16; r++) {
        int d = db * 32 + 4 * h + (r & 3) + 8 * (r >> 2);
        Ob[d] = f2bf((accO[db][r] * a0 + src[c5 * 65 + d] * a1) * inv);
      }
  }
}

// ---------------- host launch ----------------
extern "C" void kernel_launch(void* const* d_in, const int* in_sizes, int n_in,
                              void* d_out, int out_size, void* d_ws, size_t ws_size,
                              hipStream_t stream) {
  const float* q  = (const float*)d_in[0];
  const float* kv = (const float*)d_in[1];
  const float* Wq = (const float*)d_in[2];
  const float* bq = (const float*)d_in[3];
  const float* Wk = (const float*)d_in[4];
  const float* bk = (const float*)d_in[5];
  const float* Wv = (const float*)d_in[6];
  const float* bv = (const float*)d_in[7];
  const float* Wo = (const float*)d_in[8];
  const float* bo = (const float*)d_in[9];

  const size_t MB = 1u << 20;
  char* ws = (char*)d_ws;
  u16* qb  = (u16*)(ws + 0 * MB);
  u16* kvb = (u16*)(ws + 8 * MB);
  u16* wqb = (u16*)(ws + 16 * MB);
  u16* wkb = (u16*)(ws + 16 * MB + 524288);
  u16* wvb = (u16*)(ws + 17 * MB);
  u16* wob = (u16*)(ws + 17 * MB + 524288);
  u16* Qh  = (u16*)(ws + 18 * MB);   // [16][4096][64], pre-scaled by log2e/8
  u16* Kh  = (u16*)(ws + 26 * MB);   // [16][4096][64]
  u16* Vt  = (u16*)(ws + 34 * MB);   // [16][64][4096]
  u16* aO  = (u16*)(ws + 42 * MB);   // [8192][512]

  cvt_bf16_kernel<<<dim3(4096), dim3(256), 0, stream>>>(q, qb, 1048576);
  cvt_bf16_kernel<<<dim3(4096), dim3(256), 0, stream>>>(kv, kvb, 1048576);
  cvt4_kernel<<<dim3(256, 4), dim3(256), 0, stream>>>(Wq, Wk, Wv, Wo, wqb, wkb, wvb, wob);

  const float qscale = 0.125f * 1.44269504088896340736f;  // (1/sqrt(64)) * log2(e)
  gemm_bt<0><<<dim3(64, 4), dim3(256), 0, stream>>>(qb,  wqb, bq, (void*)Qh, qscale);
  gemm_bt<0><<<dim3(64, 4), dim3(256), 0, stream>>>(kvb, wkb, bk, (void*)Kh, 1.0f);
  gemm_bt<1><<<dim3(64, 4), dim3(256), 0, stream>>>(kvb, wvb, bv, (void*)Vt, 1.0f);

  attn_kernel<<<dim3(512), dim3(512), 0, stream>>>(Qh, Kh, Vt, aO);

  gemm_bt<2><<<dim3(64, 4), dim3(256), 0, stream>>>(aO, wob, bo, d_out, 1.0f);
}